// Round 8
// baseline (51.695 us; speedup 1.0000x reference)
//
#include <hip/hip_runtime.h>

// ---- problem geometry ----
#define NN 160             // input dim
#define MM 152             // output dim (160-9+1)
#define TO 16              // output tile edge (y and x)
#define TI 24              // input tile edge = TO+8
#define PSTR 28            // Pld row stride (floats), 16B-aligned
#define PCH  (TI*PSTR+4)   // 676: Pld channel stride
#define XR   20            // xs row stride (x innermost: 16 + 4 pad), 80B = 5x16B
#define XCH  (TI*XR+4)     // 484: xs channel stride (1936B, 16B-aligned)
#define YR   20            // ys y stride (x innermost: 16 + 4 pad)
#define YCH  (TO*YR+4)     // 324: ys channel stride (1296B, 16B-aligned)
#define ZC 19              // z-outputs per block (152 = 8*19)
#define PL (ZC+8)          // 27 input planes per block
#define KMAX (PL+2)        // 29: pipeline steps 0..29
#define NZ 8
#define NTX 10
#define NTILE 100
#define NBLK (NTILE*NZ)    // 800
#define INV_WIN (1.0f/729.0f)

__device__ __forceinline__ float cc_of(const float* s) {
    float cross = fmaf(-s[0] * s[1], INV_WIN, s[4]);
    float iv    = fmaf(-s[0] * s[0], INV_WIN, s[2]);
    float jv    = fmaf(-s[1] * s[1], INV_WIN, s[3]);
    return (cross * cross) / (iv * jv + 1e-6f);
}

__device__ __forceinline__ float4 f4add(float4 a, float4 b) {
    float4 r; r.x=a.x+b.x; r.y=a.y+b.y; r.z=a.z+b.z; r.w=a.w+b.w; return r;
}
__device__ __forceinline__ float4 f4sub(float4 a, float4 b) {
    float4 r; r.x=a.x-b.x; r.y=a.y-b.y; r.z=a.z-b.z; r.w=a.w-b.w; return r;
}

__global__ __launch_bounds__(256, 4) void lncc_fused(
    const float* __restrict__ I, const float* __restrict__ J,
    float* __restrict__ partial)
{
    __shared__ float Pld[2 * PCH];        // raw I,J plane tile (5408 B)
    __shared__ float xsb[2][5 * XCH];     // x-sums [c][row][x], dbuf (19360 B)
    __shared__ float ysb[2][5 * YCH];     // xy-sums [c][y][x], dbuf (12960 B)
    __shared__ float red[4];

    const int tid  = threadIdx.x;
    const int orig = blockIdx.x;
    const int bid  = (orig & 7) * NTILE + (orig >> 3);  // XCD-chunk swizzle (800%8==0)
    const int tile = bid % NTILE;
    const int zc   = bid / NTILE;
    const int x0 = (tile % NTX) * TO;
    const int y0 = (tile / NTX) * TO;
    const int z0 = zc * ZC;

    const int yl = tid >> 4, xl = tid & 15;
    const bool valid = (x0 + xl < MM) && (y0 + yl < MM);

    // loader mapping (tid < 144): 24 rows x 6 quads, one float4 per array
    const int lrow = tid / 6;
    const int lq   = tid - 6 * lrow;
    const int gy   = min(y0 + lrow, NN - 1);   // clamps only feed invalid outputs
    const int gx   = min(x0 + lq * 4, NN - 4);
    const size_t pbase = (size_t)gy * NN + gx;

    // X mapping (tid < 96): (row, x-quad); all 5 channels, float4 stores
    const int rowX = tid >> 2;
    const int xbX  = (tid & 3) * 4;

    // Y mapping (tid 192..231): 40 items = (ch, x-quad, y-half); float4 path
    const int eY  = tid - 192;
    const int cY  = eY >> 3;
    const int xbY = ((eY >> 1) & 3) * 4;
    const int ybY = (eY & 1) * 8;

    float4 pI, pJ;                             // prefetch registers
    if (tid < 144) {
        size_t a = (size_t)z0 * (NN * NN) + pbase;
        pI = *(const float4*)(I + a);
        pJ = *(const float4*)(J + a);
    }

    float ring[9][5];                          // z-window history (static idx only)
    float sz[5] = {0.f, 0.f, 0.f, 0.f, 0.f};
    float cc_acc = 0.f;

    for (int kb = 0; kb <= KMAX; kb += 9) {
#pragma unroll
        for (int ki = 0; ki < 9; ++ki) {
            const int k = kb + ki;             // pipeline step (block-uniform)
            if (k > KMAX) continue;

            // ============== Group 1: X(k-1) | Y(k-2), disjoint threads ==============
            if (k >= 1 && k <= PL && tid < 96) {
                // X: read 12-float I,J windows once; 5 channels; float4 stores
                const int b = (k - 1) & 1;
                const float4* Ir = (const float4*)&Pld[rowX * PSTR + xbX];
                const float4* Jr = (const float4*)&Pld[PCH + rowX * PSTR + xbX];
                float4 i0 = Ir[0], i1 = Ir[1], i2 = Ir[2];
                float4 j0 = Jr[0], j1 = Jr[1], j2 = Jr[2];
                float iv[12], jv[12];
                iv[0]=i0.x; iv[1]=i0.y; iv[2]=i0.z; iv[3]=i0.w;
                iv[4]=i1.x; iv[5]=i1.y; iv[6]=i1.z; iv[7]=i1.w;
                iv[8]=i2.x; iv[9]=i2.y; iv[10]=i2.z; iv[11]=i2.w;
                jv[0]=j0.x; jv[1]=j0.y; jv[2]=j0.z; jv[3]=j0.w;
                jv[4]=j1.x; jv[5]=j1.y; jv[6]=j1.z; jv[7]=j1.w;
                jv[8]=j2.x; jv[9]=j2.y; jv[10]=j2.z; jv[11]=j2.w;
#pragma unroll
                for (int c = 0; c < 5; ++c) {   // static unroll: selects fold away
                    float m[12];
#pragma unroll
                    for (int t = 0; t < 12; ++t) {
                        float av = (c & 1) ? jv[t] : iv[t];        // 0,2,4->I 1,3->J
                        float bv = (c < 2) ? 1.0f : ((c == 2) ? iv[t] : jv[t]);
                        m[t] = av * bv;
                    }
                    float s0 = m[0]+m[1]+m[2]+m[3]+m[4]+m[5]+m[6]+m[7]+m[8];
                    float s1 = s0 + m[9]  - m[0];
                    float s2 = s1 + m[10] - m[1];
                    float s3 = s2 + m[11] - m[2];
                    float4 o; o.x = s0; o.y = s1; o.z = s2; o.w = s3;
                    *(float4*)&xsb[b][c * XCH + rowX * XR + xbX] = o;
                }
            }
            if (k >= 2 && k <= PL + 1 && tid >= 192 && tid < 232) {
                // Y: 16 rows x 4 cols via b128, float4 sliding 9-tap, 8 b128 stores
                const int b = (k - 2) & 1;
                const float* Rb = &xsb[b][cY * XCH + xbY];
                float4 w[16];
#pragma unroll
                for (int j = 0; j < 16; ++j)
                    w[j] = *(const float4*)&Rb[(ybY + j) * XR];
                float4 o = f4add(f4add(f4add(f4add(w[0], w[1]), f4add(w[2], w[3])),
                                 f4add(f4add(w[4], w[5]), f4add(w[6], w[7]))), w[8]);
                float* Wb = &ysb[b][cY * YCH + xbY];
                *(float4*)&Wb[ybY * YR] = o;
#pragma unroll
                for (int t = 1; t < 8; ++t) {
                    o = f4add(o, f4sub(w[t + 8], w[t - 1]));
                    *(float4*)&Wb[(ybY + t) * YR] = o;
                }
            }
            __syncthreads();

            // ============== Group 2: commit(k)+prefetch(k+1) | Z(k-3) ==============
            if (k <= PL - 1 && tid < 144) {
                *(float4*)&Pld[lrow * PSTR + lq * 4]       = pI;
                *(float4*)&Pld[PCH + lrow * PSTR + lq * 4] = pJ;
                if (k <= PL - 2) {
                    size_t adr = (size_t)(z0 + k + 1) * (NN * NN) + pbase;
                    pI = *(const float4*)(I + adr);
                    pJ = *(const float4*)(J + adr);
                }
            }
            if (k >= 3) {
                // Z: per-column sliding z-window over ys[(k-3)&1] + cc
                const int b = (k - 3) & 1;
                const int slot  = (ki + 6) % 9;   // (k-3)%9, static per unrolled copy
                const int slot2 = (ki + 7) % 9;   // (k-3-8)%9
                float v[5];
#pragma unroll
                for (int c = 0; c < 5; ++c) {
                    v[c] = ysb[b][c * YCH + yl * YR + xl];
                    sz[c] += v[c];
                    ring[slot][c] = v[c];
                }
                if (k >= 11) {                    // pz = k-3 >= 8: emit output
                    cc_acc += valid ? cc_of(sz) : 0.f;
#pragma unroll
                    for (int c = 0; c < 5; ++c) sz[c] -= ring[slot2][c];
                }
            }
            __syncthreads();
        }
    }

    // ---- block reduction (deterministic) ----
    for (int off = 32; off > 0; off >>= 1)
        cc_acc += __shfl_down(cc_acc, off, 64);
    if ((tid & 63) == 0) red[tid >> 6] = cc_acc;
    __syncthreads();
    if (tid == 0) partial[orig] = red[0] + red[1] + red[2] + red[3];
}

// ---- final deterministic reduction over 800 partials ----
__global__ __launch_bounds__(256) void lncc_final(
    const float* __restrict__ partial, float* __restrict__ out)
{
    double s = 0.0;
    for (int i = threadIdx.x; i < NBLK; i += 256)
        s += (double)partial[i];
    for (int off = 32; off > 0; off >>= 1)
        s += __shfl_down(s, off, 64);
    __shared__ double red[4];
    const int lane = threadIdx.x & 63, wid = threadIdx.x >> 6;
    if (lane == 0) red[wid] = s;
    __syncthreads();
    if (threadIdx.x == 0) {
        double tot = red[0] + red[1] + red[2] + red[3];
        out[0] = (float)(1.0 - tot / ((double)MM * MM * MM));
    }
}

extern "C" void kernel_launch(void* const* d_in, const int* in_sizes, int n_in,
                              void* d_out, int out_size, void* d_ws, size_t ws_size,
                              hipStream_t stream) {
    const float* I = (const float*)d_in[0];
    const float* J = (const float*)d_in[1];
    // d_in[2]: all-ones 9x9x9 filter, folded into the box-sum algebra.

    float* partial = (float*)d_ws;             // NBLK floats

    lncc_fused<<<NBLK, 256, 0, stream>>>(I, J, partial);
    lncc_final<<<1,    256, 0, stream>>>(partial, (float*)d_out);
    (void)in_sizes; (void)n_in; (void)out_size; (void)ws_size;
}

// Round 9
// 39.032 us; speedup vs baseline: 1.3244x; 1.3244x over previous
//
#include <hip/hip_runtime.h>

// ---- problem geometry ----
#define NN 160             // input dim
#define MM 152             // output dim (160-9+1)
#define TO 16              // output tile edge (y and x)
#define TI 24              // input tile edge = TO+8
#define PSTR 24            // Pld row stride (floats), 16B-aligned
#define PCH  (TI*PSTR)     // 576: Pld image stride (uniform per inst -> no conflict effect)
#define XROW 28            // xs x-dim stride (row dim inner); 112q%32=16q -> 2-way stores
#define XCH  (TO*XROW)     // 448: xs channel stride
#define YROW 20            // ys x-dim stride (y dim inner); 20x%32 spreads 8 quads
#define YCH  (TO*YROW)     // 320: ys channel stride
#define ZC 19              // z-outputs per block (152 = 8*19)
#define PL (ZC+8)          // 27 input planes per block
#define KMAX (PL+2)        // 29: pipeline steps 0..29
#define NZ 8
#define NTX 10
#define NTILE 100
#define NBLK (NTILE*NZ)    // 800
#define INV_WIN (1.0f/729.0f)

__device__ __forceinline__ float cc_of(const float* s) {
    float cross = fmaf(-s[0] * s[1], INV_WIN, s[4]);
    float iv    = fmaf(-s[0] * s[0], INV_WIN, s[2]);
    float jv    = fmaf(-s[1] * s[1], INV_WIN, s[3]);
    return (cross * cross) / (iv * jv + 1e-6f);
}

__global__ __launch_bounds__(256, 4) void lncc_fused(
    const float* __restrict__ I, const float* __restrict__ J,
    float* __restrict__ partial)
{
    // One barrier per pipeline step: ALL buffers parity-double-buffered.
    __shared__ float Pld[2][2 * PCH];     // [parity][I|J plane tile]   9216 B
    __shared__ float xsb[2][5 * XCH];     // x-sums [c][x][row], dbuf  17920 B
    __shared__ float ysb[2][5 * YCH];     // xy-sums [c][x][y], dbuf   12800 B
    __shared__ float red[4];              //                            total 39952 B

    const int tid  = threadIdx.x;
    const int orig = blockIdx.x;
    const int bid  = (orig & 7) * NTILE + (orig >> 3);  // XCD-chunk swizzle (800%8==0)
    const int tile = bid % NTILE;
    const int zc   = bid / NTILE;
    const int x0 = (tile % NTX) * TO;
    const int y0 = (tile / NTX) * TO;
    const int z0 = zc * ZC;

    const int yl = tid >> 4, xl = tid & 15;
    const bool valid = (x0 + xl < MM) && (y0 + yl < MM);

    // loader mapping (tid < 144): 24 rows x 6 quads, one float4 per image
    const int lrow = tid / 6;
    const int lq   = tid - 6 * lrow;
    const int gy   = min(y0 + lrow, NN - 1);   // clamps only feed invalid outputs
    const int gx   = min(x0 + lq * 4, NN - 4);
    const size_t pbase = (size_t)gy * NN + gx;

    // X mapping (tid < 96): (row, x-quad); all 5 channels per thread
    const int rowX = tid >> 2;
    const int xbX  = (tid & 3) * 4;

    // Y mapping (tid 96..175): 80 items = (ch, x); full 24-row column per thread
    const int eY = tid - 96;
    const int cY = eY >> 4;
    const int xY = eY & 15;

    float4 pI, pJ;                             // prefetch registers
    if (tid < 144) {
        size_t a = (size_t)z0 * (NN * NN) + pbase;
        pI = *(const float4*)(I + a);
        pJ = *(const float4*)(J + a);
    }

    float ring[9][5];                          // z-window history (static idx only)
    float sz[5] = {0.f, 0.f, 0.f, 0.f, 0.f};
    float cc_acc = 0.f;

    for (int kb = 0; kb <= KMAX; kb += 9) {
#pragma unroll
        for (int ki = 0; ki < 9; ++ki) {
            const int k = kb + ki;             // pipeline step (block-uniform)
            if (k > KMAX) continue;

            // ---- commit(k) -> Pld[k&1], prefetch(k+1) (issue global loads first) ----
            if (k <= PL - 1 && tid < 144) {
                float* P = &Pld[k & 1][0];
                *(float4*)&P[lrow * PSTR + lq * 4]       = pI;
                *(float4*)&P[PCH + lrow * PSTR + lq * 4] = pJ;
                if (k <= PL - 2) {
                    size_t adr = (size_t)(z0 + k + 1) * (NN * NN) + pbase;
                    pI = *(const float4*)(I + adr);
                    pJ = *(const float4*)(J + adr);
                }
            }

            // ---- X(k-1): Pld[(k-1)&1] -> xsb[(k-1)&1] ----
            if (k >= 1 && k <= PL && tid < 96) {
                const int b = (k - 1) & 1;
                const float* P = &Pld[b][0];
                const float4* Ir = (const float4*)&P[rowX * PSTR + xbX];
                const float4* Jr = (const float4*)&P[PCH + rowX * PSTR + xbX];
                float4 i0 = Ir[0], i1 = Ir[1], i2 = Ir[2];
                float4 j0 = Jr[0], j1 = Jr[1], j2 = Jr[2];
                float iv[12], jv[12];
                iv[0]=i0.x; iv[1]=i0.y; iv[2]=i0.z; iv[3]=i0.w;
                iv[4]=i1.x; iv[5]=i1.y; iv[6]=i1.z; iv[7]=i1.w;
                iv[8]=i2.x; iv[9]=i2.y; iv[10]=i2.z; iv[11]=i2.w;
                jv[0]=j0.x; jv[1]=j0.y; jv[2]=j0.z; jv[3]=j0.w;
                jv[4]=j1.x; jv[5]=j1.y; jv[6]=j1.z; jv[7]=j1.w;
                jv[8]=j2.x; jv[9]=j2.y; jv[10]=j2.z; jv[11]=j2.w;
#pragma unroll
                for (int c = 0; c < 5; ++c) {   // static unroll: selects fold away
                    float m[12];
#pragma unroll
                    for (int t = 0; t < 12; ++t) {
                        float av = (c & 1) ? jv[t] : iv[t];        // 0,2,4->I 1,3->J
                        float bv = (c < 2) ? 1.0f : ((c == 2) ? iv[t] : jv[t]);
                        m[t] = av * bv;
                    }
                    float s = m[0]+m[1]+m[2]+m[3]+m[4]+m[5]+m[6]+m[7]+m[8];
                    float* W = &xsb[b][c * XCH + rowX];
                    W[xbX * XROW] = s;
#pragma unroll
                    for (int t = 1; t < 4; ++t) {
                        s += m[t + 8] - m[t - 1];
                        W[(xbX + t) * XROW] = s;
                    }
                }
            }

            // ---- Y(k-2): xsb[(k-2)&1] -> ysb[(k-2)&1] ----
            if (k >= 2 && k <= PL + 1 && tid >= 96 && tid < 176) {
                const int b = (k - 2) & 1;
                const float4* R = (const float4*)&xsb[b][cY * XCH + xY * XROW];
                float4 w0 = R[0], w1 = R[1], w2 = R[2], w3 = R[3], w4 = R[4], w5 = R[5];
                float m[24];
                m[0]=w0.x;  m[1]=w0.y;  m[2]=w0.z;  m[3]=w0.w;
                m[4]=w1.x;  m[5]=w1.y;  m[6]=w1.z;  m[7]=w1.w;
                m[8]=w2.x;  m[9]=w2.y;  m[10]=w2.z; m[11]=w2.w;
                m[12]=w3.x; m[13]=w3.y; m[14]=w3.z; m[15]=w3.w;
                m[16]=w4.x; m[17]=w4.y; m[18]=w4.z; m[19]=w4.w;
                m[20]=w5.x; m[21]=w5.y; m[22]=w5.z; m[23]=w5.w;
                float o[16];
                float s = m[0]+m[1]+m[2]+m[3]+m[4]+m[5]+m[6]+m[7]+m[8];
                o[0] = s;
#pragma unroll
                for (int t = 1; t < 16; ++t) {
                    s += m[t + 8] - m[t - 1];
                    o[t] = s;
                }
                float4* Wv = (float4*)&ysb[b][cY * YCH + xY * YROW];
                float4 oa = {o[0],  o[1],  o[2],  o[3]};
                float4 ob = {o[4],  o[5],  o[6],  o[7]};
                float4 oc = {o[8],  o[9],  o[10], o[11]};
                float4 od = {o[12], o[13], o[14], o[15]};
                Wv[0] = oa; Wv[1] = ob; Wv[2] = oc; Wv[3] = od;
            }

            // ---- Z(k-3): ysb[(k-3)&1] sliding z-window + cc ----
            if (k >= 3) {
                const int b = (k - 3) & 1;
                const int slot  = (ki + 6) % 9;   // (k-3)%9, static per unrolled copy
                const int slot2 = (ki + 7) % 9;   // (k-3-8)%9
                float v[5];
#pragma unroll
                for (int c = 0; c < 5; ++c) {
                    v[c] = ysb[b][c * YCH + xl * YROW + yl];
                    sz[c] += v[c];
                    ring[slot][c] = v[c];
                }
                if (k >= 11) {                    // pz = k-3 >= 8: emit output
                    cc_acc += valid ? cc_of(sz) : 0.f;
#pragma unroll
                    for (int c = 0; c < 5; ++c) sz[c] -= ring[slot2][c];
                }
            }

            __syncthreads();                      // single barrier per step
        }
    }

    // ---- block reduction (deterministic) ----
    for (int off = 32; off > 0; off >>= 1)
        cc_acc += __shfl_down(cc_acc, off, 64);
    if ((tid & 63) == 0) red[tid >> 6] = cc_acc;
    __syncthreads();
    if (tid == 0) partial[orig] = red[0] + red[1] + red[2] + red[3];
}

// ---- final deterministic reduction over 800 partials ----
__global__ __launch_bounds__(256) void lncc_final(
    const float* __restrict__ partial, float* __restrict__ out)
{
    double s = 0.0;
    for (int i = threadIdx.x; i < NBLK; i += 256)
        s += (double)partial[i];
    for (int off = 32; off > 0; off >>= 1)
        s += __shfl_down(s, off, 64);
    __shared__ double red[4];
    const int lane = threadIdx.x & 63, wid = threadIdx.x >> 6;
    if (lane == 0) red[wid] = s;
    __syncthreads();
    if (threadIdx.x == 0) {
        double tot = red[0] + red[1] + red[2] + red[3];
        out[0] = (float)(1.0 - tot / ((double)MM * MM * MM));
    }
}

extern "C" void kernel_launch(void* const* d_in, const int* in_sizes, int n_in,
                              void* d_out, int out_size, void* d_ws, size_t ws_size,
                              hipStream_t stream) {
    const float* I = (const float*)d_in[0];
    const float* J = (const float*)d_in[1];
    // d_in[2]: all-ones 9x9x9 filter, folded into the box-sum algebra.

    float* partial = (float*)d_ws;             // NBLK floats

    lncc_fused<<<NBLK, 256, 0, stream>>>(I, J, partial);
    lncc_final<<<1,    256, 0, stream>>>(partial, (float*)d_out);
    (void)in_sizes; (void)n_in; (void)out_size; (void)ws_size;
}